// Round 5
// baseline (241.013 us; speedup 1.0000x reference)
//
#include <hip/hip_runtime.h>

// Zero timestep t (t & 3 == mask_idx) of x: [8, 8192, 512] fp32.
// Memory-bound. Floor ~= (96..128 MiB read + 128 MiB write) / 6.3 TB/s ~= 36 us.
//
// Round-4 evidence: nt-store version = 80.5 us, 2.3 TB/s HBM, VGPR=32
// (compiler serialized load->store pairs). Harness fill proves plain stores
// sustain 6.7 TB/s at 9.5% occupancy. This round: PLAIN stores + explicit
// 8-deep load batches (clustered global_load_dwordx4, then clustered stores).
//
// Geometry: 2048 blocks x 256 threads, 16 f32x4/thread at stride 524288 f32x4.
// stride/128 = 4096 timesteps (mult of 4) -> each thread's (t&3) phase is
// loop-invariant and wave-uniform -> masked waves do 16 pure stores, never load.

#define PERIOD 4

typedef float f32x4 __attribute__((ext_vector_type(4)));

__global__ __launch_bounds__(256)
void pd_mask_fast(const f32x4* __restrict__ x,
                  const int* __restrict__ mask_p,
                  f32x4* __restrict__ out) {
    constexpr int STRIDE = 2048 * 256;     // total threads (f32x4 units)
    const int tid = blockIdx.x * 256 + threadIdx.x;
    const int m = *mask_p;                 // uniform scalar load
    // t = f32x4_idx >> 7 (128 f32x4 per timestep); phase loop-invariant.
    if (((tid >> 7) & (PERIOD - 1)) == m) {
        const f32x4 zero = (f32x4){0.f, 0.f, 0.f, 0.f};
        #pragma unroll
        for (int k = 0; k < 16; ++k)
            out[tid + k * STRIDE] = zero;
    } else {
        // Two rounds of: 8 independent loads clustered, then 8 stores.
        #pragma unroll
        for (int r = 0; r < 2; ++r) {
            f32x4 v[8];
            #pragma unroll
            for (int k = 0; k < 8; ++k)
                v[k] = x[tid + (r * 8 + k) * STRIDE];
            #pragma unroll
            for (int k = 0; k < 8; ++k)
                out[tid + (r * 8 + k) * STRIDE] = v[k];
        }
    }
}

// Generic fallback (any size).
__global__ __launch_bounds__(256)
void pd_mask_generic(const f32x4* __restrict__ x,
                     const int* __restrict__ mask_p,
                     f32x4* __restrict__ out, int n4) {
    const int m = *mask_p;
    const f32x4 zero = (f32x4){0.f, 0.f, 0.f, 0.f};
    const int stride = gridDim.x * blockDim.x;
    for (int i = blockIdx.x * blockDim.x + threadIdx.x; i < n4; i += stride) {
        const int t = i >> 7;
        out[i] = ((t & (PERIOD - 1)) == m) ? zero : x[i];
    }
}

extern "C" void kernel_launch(void* const* d_in, const int* in_sizes, int n_in,
                              void* d_out, int out_size, void* d_ws, size_t ws_size,
                              hipStream_t stream) {
    const f32x4* x      = (const f32x4*)d_in[0];
    const int*   mask_p = (const int*)d_in[1];
    f32x4*       out    = (f32x4*)d_out;

    const int n4 = out_size / 4;           // 8388608 f32x4
    constexpr int BLOCK = 256, GRID = 2048, ITERS = 16;

    if (n4 == GRID * BLOCK * ITERS) {
        pd_mask_fast<<<GRID, BLOCK, 0, stream>>>(x, mask_p, out);
    } else {
        int grid = (n4 + BLOCK - 1) / BLOCK;
        if (grid > 2048) grid = 2048;
        pd_mask_generic<<<grid, BLOCK, 0, stream>>>(x, mask_p, out, n4);
    }
}

// Round 7
// 228.481 us; speedup vs baseline: 1.0549x; 1.0549x over previous
//
#include <hip/hip_runtime.h>

// Zero timestep t (t & 3 == mask_idx) of x: [8, 8192, 512] fp32.
// Memory-bound. Floor ~= (96 MiB read + 128 MiB write) / 6.3 TB/s ~= 36 us.
//
// History: R1 grid-slab stride ~73us; R4 +nt stores 80.5us (2.3 TB/s HBM,
// Occ 46%); R5 +clustered loads ~75-80us. All share the whole-grid-slab
// stride (per-thread accesses 8 MiB apart -> every access a new DRAM row).
// This round: BLOCK-CONTIGUOUS STREAMING (canonical copy pattern).
//
// Geometry: 1024 blocks x 512 threads x 16 iters; i = bid*8192 + k*512 + tid.
// Each block streams 128 KiB contiguous; each 2-wave half-quarter owns one
// 2-KiB timestep per iteration. Since k advances t by exactly 4, the phase
// t&3 == (tid>>7)&3 is LOOP-INVARIANT and wave-uniform: 2 of 8 waves per
// block do pure zero-stores (never load), the rest stream copy.
// 1024 blocks * 8 waves = 32 waves/CU exactly; __launch_bounds__(512,8)
// pins VGPR <= 64 so occupancy holds.

#define PERIOD 4

typedef float f32x4 __attribute__((ext_vector_type(4)));

__global__ __launch_bounds__(512, 8)
void pd_mask_stream(const f32x4* __restrict__ x,
                    const int* __restrict__ mask_p,
                    f32x4* __restrict__ out) {
    constexpr int ITERS = 16;
    constexpr int BLOCK = 512;
    const int tid  = threadIdx.x;
    const int base = blockIdx.x * (BLOCK * ITERS) + tid;   // max ~8.4M, fits int
    const int m = *mask_p;                                 // uniform scalar load
    const int phase = (tid >> 7) & 3;                      // t&3, loop-invariant
    if (phase == m) {
        const f32x4 zero = (f32x4){0.f, 0.f, 0.f, 0.f};
        #pragma unroll
        for (int k = 0; k < ITERS; ++k)
            out[base + k * BLOCK] = zero;
    } else {
        #pragma unroll
        for (int r = 0; r < 2; ++r) {
            f32x4 v[8];                                    // 32 VGPRs in flight
            #pragma unroll
            for (int k = 0; k < 8; ++k)
                v[k] = x[base + (r * 8 + k) * BLOCK];
            #pragma unroll
            for (int k = 0; k < 8; ++k)
                out[base + (r * 8 + k) * BLOCK] = v[k];
        }
    }
}

// Generic fallback (any size).
__global__ __launch_bounds__(256)
void pd_mask_generic(const f32x4* __restrict__ x,
                     const int* __restrict__ mask_p,
                     f32x4* __restrict__ out, int n4) {
    const int m = *mask_p;
    const f32x4 zero = (f32x4){0.f, 0.f, 0.f, 0.f};
    const int stride = gridDim.x * blockDim.x;
    for (int i = blockIdx.x * blockDim.x + threadIdx.x; i < n4; i += stride) {
        const int t = i >> 7;
        out[i] = ((t & (PERIOD - 1)) == m) ? zero : x[i];
    }
}

extern "C" void kernel_launch(void* const* d_in, const int* in_sizes, int n_in,
                              void* d_out, int out_size, void* d_ws, size_t ws_size,
                              hipStream_t stream) {
    const f32x4* x      = (const f32x4*)d_in[0];
    const int*   mask_p = (const int*)d_in[1];
    f32x4*       out    = (f32x4*)d_out;

    const int n4 = out_size / 4;                 // 8388608 f32x4
    constexpr int GRID = 1024, BLOCK = 512, ITERS = 16;

    if (n4 == GRID * BLOCK * ITERS) {
        pd_mask_stream<<<GRID, BLOCK, 0, stream>>>(x, mask_p, out);
    } else {
        int grid = (n4 + 255) / 256;
        if (grid > 2048) grid = 2048;
        pd_mask_generic<<<grid, 256, 0, stream>>>(x, mask_p, out, n4);
    }
}